// Round 14
// baseline (508.931 us; speedup 1.0000x reference)
//
#include <hip/hip_runtime.h>
#include <math.h>

#define NROWS 8192
#define DIM   1024
#define DIM2  2048           // merged hi|lo K dimension
#define KSEL  5
#define TOPK  6
#define QB    128            // queries per block
#define KBB   256            // keys per block
#define NKB   (NROWS / KBB)  // key blocks = 32 (also lists per row)
#define NQB   (NROWS / QB)   // query blocks = 64
#define PS    51             // mbuf per-query stride in float2 (pad 48->51)

typedef __attribute__((ext_vector_type(8))) short bf16x8;
typedef __attribute__((ext_vector_type(4))) float f32x4;

// ---------------------------------------------------------------------------
// ws layout:
//   [0]          : int match counter   [4] : int done counter (memset 8 B)
//   [256]        : Q2 bf16[8192][2048]  (hi | lo, XOR-swizzled)   32 MB
//   [+32M]       : K2 bf16[8192][2048]  (hi | lo, XOR-swizzled)   32 MB
//   [+64M]       : partials float2[8192][32][6]  (12.6 MB)
//
// Round-14 = round-13 with two changes:
//  * grid dims swapped (x=kb, y=qb): resident 512 blocks = all 32 K-slices
//    x 16 q-blocks, so K2 (32 MB) stays L2/L3-resident across all rounds
//    and Q2 streams once. r13 FETCH=220 MB vs 64 MB unique input = L2/L3
//    thrash from qb-fastest order; the HBM-miss latency (~900 vs ~200 cyc,
//    m126) sits on the vmcnt(0) barrier-drain critical path.
//  * finalize fused into merge via device-scope done-counter (one fewer
//    launch). gemm kernel body unchanged (347 us, conflicts 5.7e5).
// ---------------------------------------------------------------------------

__device__ __forceinline__ unsigned short f2bf(float x) {
    unsigned u = __float_as_uint(x);
    unsigned r = (u + 0x7fffu + ((u >> 16) & 1u)) >> 16;   // RNE
    return (unsigned short)r;
}
__device__ __forceinline__ float bf2f(unsigned short h) {
    return __uint_as_float(((unsigned)h) << 16);
}

// full tie-break compare (merge paths — arbitrary id order there)
__device__ __forceinline__ bool better(float v, int id, float v2, int id2) {
    return (v > v2) || (v == v2 && id < id2);
}
__device__ __forceinline__ void insert6(float v, int id, float* tv, int* ti) {
    if (!better(v, id, tv[TOPK - 1], ti[TOPK - 1])) return;
    int j = TOPK - 1;
    while (j > 0 && better(v, id, tv[j - 1], ti[j - 1])) {
        tv[j] = tv[j - 1]; ti[j] = ti[j - 1]; --j;
    }
    tv[j] = v; ti[j] = id;
}

// branchless strict insert (ascending-id stream => strict '>' is exact).
__device__ __forceinline__ void ins6(float v, int id, float* tv, int* ti) {
    if (v <= tv[5]) return;
    bool gt[6];
#pragma unroll
    for (int j = 0; j < 6; ++j) gt[j] = v > tv[j];
#pragma unroll
    for (int j = 5; j >= 1; --j)
        if (gt[j - 1]) { tv[j] = tv[j - 1]; ti[j] = ti[j - 1]; }
    if (gt[0]) { tv[0] = v; ti[0] = id; }
#pragma unroll
    for (int j = 1; j < 6; ++j)
        if (gt[j] && !gt[j - 1]) { tv[j] = v; ti[j] = id; }
}

__device__ __forceinline__ void async16(const unsigned short* g, unsigned short* l) {
    __builtin_amdgcn_global_load_lds(
        (const __attribute__((address_space(1))) void*)g,
        (__attribute__((address_space(3))) void*)l, 16, 0, 0);
}

// --- 1) normalize + split hi/lo bf16, coalesced loads via k-permutation -----
__global__ __launch_bounds__(128) void prep_kernel(
        const float* __restrict__ q, const float* __restrict__ kb,
        unsigned short* __restrict__ Q2, unsigned short* __restrict__ K2) {
    const int b = blockIdx.x;
    const bool isQ = (b < NROWS);
    const int r = isQ ? b : b - NROWS;
    const float* src = (isQ ? q : kb) + (size_t)r * DIM;
    unsigned short* D = (isQ ? Q2 : K2) + (size_t)r * DIM2;

    const int t = threadIdx.x;          // 0..127
    float4 v0 = *(const float4*)(src + t * 4);          // coalesced
    float4 v1 = *(const float4*)(src + 512 + t * 4);    // coalesced
    float s = v0.x * v0.x + v0.y * v0.y + v0.z * v0.z + v0.w * v0.w
            + v1.x * v1.x + v1.y * v1.y + v1.z * v1.z + v1.w * v1.w;
    for (int o = 32; o; o >>= 1) s += __shfl_down(s, o, 64);
    __shared__ float wsum[2];
    __shared__ float inv_s;
    int lane = t & 63, wid = t >> 6;
    if (lane == 0) wsum[wid] = s;
    __syncthreads();
    if (t == 0)
        inv_s = 1.0f / fmaxf(sqrtf(wsum[0] + wsum[1]), 1e-12f);
    __syncthreads();
    const float inv = inv_s;

    float xs[8] = {v0.x * inv, v0.y * inv, v0.z * inv, v0.w * inv,
                   v1.x * inv, v1.y * inv, v1.z * inv, v1.w * inv};
    bf16x8 hi, lo;
#pragma unroll
    for (int i = 0; i < 8; ++i) {
        unsigned short h = f2bf(xs[i]);
        hi[i] = (short)h;
        lo[i] = (short)f2bf(xs[i] - bf2f(h));
    }
    // chunk t: k-block t>>3, chunk-in-block t&7, swizzled by row&7
    const int off = (t >> 3) * 64 + (((t & 7) ^ (r & 7)) * 8);
    *(bf16x8*)(D + off)       = hi;
    *(bf16x8*)(D + DIM + off) = lo;
}

// --- 2) 256x128 transposed MFMA GEMM + in-register top-6 --------------------
// grid: x = key-block (32), y = query-block (64) — K2-resident dispatch order
__global__ __launch_bounds__(256, 2) void gemm_topk_kernel(
        const unsigned short* __restrict__ Q2, const unsigned short* __restrict__ K2,
        float2* __restrict__ partials) {
    // K-loop: Ks[256*64] (32 KB) + Qs[128*64] (16 KB); merge: 128*PS float2
    __shared__ __align__(16) char smem[53248];
    unsigned short* Ks = (unsigned short*)smem;          // A-operand (keys)
    unsigned short* Qs = Ks + KBB * 64;                  // B-operand (queries)
    float2* mbuf = (float2*)smem;                        // [128 q][PS]

    const int tid = threadIdx.x;
    const int w = tid >> 6, l = tid & 63;
    const int l15 = l & 15, l4 = l >> 4;
    const int qbase = blockIdx.y * QB;
    const int kbase = blockIdx.x * KBB;
    const int wkh = w & 1;               // key half   (128 keys)
    const int wqh = w >> 1;              // query half (64 queries)

    const int arow  = tid >> 3;          // 0..31 (+ j*32)
    const int akoff = (tid & 7) * 8;     // swizzled position within k-block

    const int xr = l15 & 7;
    const int fa_row = (wkh * 128 + l15) * 64;   // + mt*1024
    const int fb_row = (wqh * 64 + l15) * 64;    // + nt*1024

    const size_t qstage = (size_t)(qbase + arow) * DIM2 + akoff;
    const size_t kstage = (size_t)(kbase + arow) * DIM2 + akoff;

    f32x4 acc[8][4];   // [mt = key-tile][nt = query-tile]
#pragma unroll
    for (int mt = 0; mt < 8; ++mt)
#pragma unroll
        for (int nt = 0; nt < 4; ++nt) acc[mt][nt] = (f32x4){0.f, 0.f, 0.f, 0.f};

#pragma unroll 1
    for (int k0 = 0; k0 < DIM2; k0 += 64) {
#pragma unroll
        for (int j = 0; j < 8; ++j)
            async16(K2 + kstage + (size_t)j * 32 * DIM2 + k0,
                    Ks + (tid + j * 256) * 8);
#pragma unroll
        for (int j = 0; j < 4; ++j)
            async16(Q2 + qstage + (size_t)j * 32 * DIM2 + k0,
                    Qs + (tid + j * 256) * 8);
        __syncthreads();   // drains vmcnt (global_load_lds)
#pragma unroll
        for (int ks = 0; ks < 2; ++ks) {
            const int p8 = ((ks * 4 + l4) ^ xr) * 8;
            bf16x8 af[8], bf[4];
#pragma unroll
            for (int mt = 0; mt < 8; ++mt)
                af[mt] = *(const bf16x8*)(Ks + fa_row + mt * 1024 + p8);
#pragma unroll
            for (int nt = 0; nt < 4; ++nt)
                bf[nt] = *(const bf16x8*)(Qs + fb_row + nt * 1024 + p8);
#pragma unroll
            for (int mt = 0; mt < 8; ++mt)
#pragma unroll
                for (int nt = 0; nt < 4; ++nt)
                    acc[mt][nt] = __builtin_amdgcn_mfma_f32_16x16x32_bf16(
                        af[mt], bf[nt], acc[mt][nt], 0, 0, 0);
        }
        __syncthreads();
    }

    // ---- in-register top-6 (once per block): 32 keys/thread per nt-list ----
    float tvl[4][6]; int til[4][6];
#pragma unroll
    for (int n = 0; n < 4; ++n)
#pragma unroll
        for (int i = 0; i < 6; ++i) { tvl[n][i] = -INFINITY; til[n][i] = 0x7fffffff; }

#pragma unroll
    for (int nt = 0; nt < 4; ++nt) {
#pragma unroll
        for (int mt = 0; mt < 8; ++mt) {
            const f32x4 a = acc[mt][nt];
            const float m4 = fmaxf(fmaxf(a.x, a.y), fmaxf(a.z, a.w));
            if (m4 > tvl[nt][5]) {
                const int kk = kbase + wkh * 128 + mt * 16 + l4 * 4;
                ins6(a.x, kk + 0, tvl[nt], til[nt]);
                ins6(a.y, kk + 1, tvl[nt], til[nt]);
                ins6(a.z, kk + 2, tvl[nt], til[nt]);
                ins6(a.w, kk + 3, tvl[nt], til[nt]);
            }
        }
    }

    // ---- block merge: 8 slots per query -> 1 list per query ---------------
    __syncthreads();                     // all K-loop LDS reads done
    const int slot = wkh * 4 + l4;       // 0..7
#pragma unroll
    for (int nt = 0; nt < 4; ++nt) {
        const int ql = wqh * 64 + nt * 16 + l15;     // local query 0..127
        float2* dst = mbuf + (size_t)ql * PS + slot * 6;
#pragma unroll
        for (int e = 0; e < 6; ++e)
            dst[e] = make_float2(tvl[nt][e], __int_as_float(til[nt][e]));
    }
    __syncthreads();

    if (tid < 128) {                     // one thread per query merges 8 lists
        float tv[6]; int ti[6];
#pragma unroll
        for (int i = 0; i < 6; ++i) { tv[i] = -INFINITY; ti[i] = 0x7fffffff; }
        const float2* src = mbuf + (size_t)tid * PS;
        for (int e = 0; e < 48; ++e) {
            float2 p = src[e];
            if (p.x < tv[5]) continue;
            insert6(p.x, __float_as_int(p.y), tv, ti);
        }
        size_t off = ((size_t)(qbase + tid) * NKB + blockIdx.x) * TOPK;
#pragma unroll
        for (int i = 0; i < 6; ++i)
            partials[off + i] = make_float2(tv[i], __int_as_float(ti[i]));
    }
}

// --- 3) parallel merge + fused finalize (device-scope handoff) --------------
__global__ __launch_bounds__(256) void merge_kernel(
        const float2* __restrict__ partials,
        const int* __restrict__ query_ids, const int* __restrict__ key_ids,
        int* __restrict__ counter, int* __restrict__ done,
        float* __restrict__ out) {
    __shared__ float2 lbuf[32][49];      // [row-in-block][8 parts * 6, pad 49]
    __shared__ int sc[32];
    const int tid  = threadIdx.x;
    const int rloc = tid >> 3;           // 0..31
    const int part = tid & 7;            // 0..7
    const int row  = blockIdx.x * 32 + rloc;

    // stage 1: each thread merges 4 of the 32 lists (24 entries, coalesced)
    float tv[6]; int ti[6];
#pragma unroll
    for (int i = 0; i < 6; ++i) { tv[i] = -INFINITY; ti[i] = 0x7fffffff; }
    const float2* src = partials + ((size_t)row * NKB + part * 4) * TOPK;
#pragma unroll
    for (int e = 0; e < 24; ++e) {
        float2 p = src[e];
        if (p.x < tv[5]) continue;
        insert6(p.x, __float_as_int(p.y), tv, ti);
    }
#pragma unroll
    for (int i = 0; i < 6; ++i)
        lbuf[rloc][part * 6 + i] = make_float2(tv[i], __int_as_float(ti[i]));
    __syncthreads();

    // stage 2: one thread per row merges the 8 partial lists + counts
    if (part == 0) {
        float tv2[6]; int ti2[6];
#pragma unroll
        for (int i = 0; i < 6; ++i) { tv2[i] = -INFINITY; ti2[i] = 0x7fffffff; }
#pragma unroll
        for (int e = 0; e < 48; ++e) {
            float2 p = lbuf[rloc][e];
            if (p.x < tv2[5]) continue;
            insert6(p.x, __float_as_int(p.y), tv2, ti2);
        }
        const int qid = query_ids[row];
        int cnt = 0;
#pragma unroll
        for (int r = 1; r < TOPK; ++r)
            cnt += (key_ids[ti2[r]] == qid) ? 1 : 0;
        sc[rloc] = cnt;
    }
    __syncthreads();
    if (tid == 0) {
        int c = 0;
#pragma unroll
        for (int i = 0; i < 32; ++i) c += sc[i];
        atomicAdd(counter, c);
        __threadfence();                 // counter-add visible before done-add
        int prev = atomicAdd(done, 1);
        if (prev == gridDim.x - 1) {     // last block finalizes
            int total = atomicAdd(counter, 0);   // coherent read
            out[0] = (float)total / (float)(NROWS * KSEL);
        }
    }
}

extern "C" void kernel_launch(void* const* d_in, const int* in_sizes, int n_in,
                              void* d_out, int out_size, void* d_ws, size_t ws_size,
                              hipStream_t stream) {
    (void)in_sizes; (void)n_in; (void)out_size; (void)ws_size;
    const int*   query_ids = (const int*)d_in[0];
    const int*   key_ids   = (const int*)d_in[1];
    const float* q         = (const float*)d_in[2];
    const float* kb        = (const float*)d_in[3];

    char* ws = (char*)d_ws;
    const size_t MB32 = (size_t)NROWS * DIM2 * sizeof(unsigned short);  // 32 MB
    int*            counter  = (int*)ws;          // [0]=matches, [1]=done
    unsigned short* Q2       = (unsigned short*)(ws + 256);
    unsigned short* K2       = (unsigned short*)(ws + 256 + MB32);
    float2*         partials = (float2*)(ws + 256 + 2 * MB32);

    hipMemsetAsync(counter, 0, 2 * sizeof(int), stream);
    prep_kernel<<<2 * NROWS, 128, 0, stream>>>(q, kb, Q2, K2);
    gemm_topk_kernel<<<dim3(NKB, NQB), 256, 0, stream>>>(Q2, K2, partials);
    merge_kernel<<<NROWS / 32, 256, 0, stream>>>(partials, query_ids, key_ids,
                                                 counter, counter + 1,
                                                 (float*)d_out);
}

// Round 15
// 456.863 us; speedup vs baseline: 1.1140x; 1.1140x over previous
//
#include <hip/hip_runtime.h>
#include <math.h>

#define NROWS 8192
#define DIM   1024
#define DIM2  2048           // merged hi|lo K dimension
#define KSEL  5
#define TOPK  6
#define QB    128            // queries per block
#define KBB   256            // keys per block
#define NKB   (NROWS / KBB)  // key blocks = 32 (also lists per row)
#define NQB   (NROWS / QB)   // query blocks = 64
#define PS    51             // mbuf per-query stride in float2 (pad 48->51)

typedef __attribute__((ext_vector_type(8))) short bf16x8;
typedef __attribute__((ext_vector_type(4))) float f32x4;

// ---------------------------------------------------------------------------
// ws layout:
//   [0]          : int match counter   [4] : int done counter (memset 8 B)
//   [256]        : Q2 bf16[8192][2048]  (hi | lo, XOR-swizzled)   32 MB
//   [+32M]       : K2 bf16[8192][2048]  (hi | lo, XOR-swizzled)   32 MB
//   [+64M]       : partials float2[8192][32][6]  (12.6 MB)
//
// Round-15 = measured-best recomposition (final):
//  * gemm + grid (x=qb, y=kb) + prep: r13 verbatim (347.4 us, 793 TF,
//    conflicts 5.7e5). r14 proved the grid swap regresses (409 us,
//    MfmaUtil 35.5->29.5) and FETCH is order-invariant (cross-XCD L2
//    duplication, ~8 x 32 MB, not thrash).
//  * merge with fused finalize: r14 (non-gemm 113 -> ~100 us).
// Ceiling: per-CU budget MFMA 318k + LDS-R 295k + LDS-W 148k ≈ 761k of
// 832k measured cyc; the residue is the vmcnt(0) barrier drain that
// learn_hip m99-m141 showed is not removable at HIP source level on this
// K-loop structure. All tile variants (r9/r10/r12/r14) land 347-409.
// ---------------------------------------------------------------------------

__device__ __forceinline__ unsigned short f2bf(float x) {
    unsigned u = __float_as_uint(x);
    unsigned r = (u + 0x7fffu + ((u >> 16) & 1u)) >> 16;   // RNE
    return (unsigned short)r;
}
__device__ __forceinline__ float bf2f(unsigned short h) {
    return __uint_as_float(((unsigned)h) << 16);
}

// full tie-break compare (merge paths — arbitrary id order there)
__device__ __forceinline__ bool better(float v, int id, float v2, int id2) {
    return (v > v2) || (v == v2 && id < id2);
}
__device__ __forceinline__ void insert6(float v, int id, float* tv, int* ti) {
    if (!better(v, id, tv[TOPK - 1], ti[TOPK - 1])) return;
    int j = TOPK - 1;
    while (j > 0 && better(v, id, tv[j - 1], ti[j - 1])) {
        tv[j] = tv[j - 1]; ti[j] = ti[j - 1]; --j;
    }
    tv[j] = v; ti[j] = id;
}

// branchless strict insert (ascending-id stream => strict '>' is exact).
__device__ __forceinline__ void ins6(float v, int id, float* tv, int* ti) {
    if (v <= tv[5]) return;
    bool gt[6];
#pragma unroll
    for (int j = 0; j < 6; ++j) gt[j] = v > tv[j];
#pragma unroll
    for (int j = 5; j >= 1; --j)
        if (gt[j - 1]) { tv[j] = tv[j - 1]; ti[j] = ti[j - 1]; }
    if (gt[0]) { tv[0] = v; ti[0] = id; }
#pragma unroll
    for (int j = 1; j < 6; ++j)
        if (gt[j] && !gt[j - 1]) { tv[j] = v; ti[j] = id; }
}

__device__ __forceinline__ void async16(const unsigned short* g, unsigned short* l) {
    __builtin_amdgcn_global_load_lds(
        (const __attribute__((address_space(1))) void*)g,
        (__attribute__((address_space(3))) void*)l, 16, 0, 0);
}

// --- 1) normalize + split hi/lo bf16, coalesced loads via k-permutation -----
// chunk t = elems {4t..4t+3, 512+4t..512+4t+3}; same permutation for Q and K
// => dot products unchanged; loads fully coalesced.
__global__ __launch_bounds__(128) void prep_kernel(
        const float* __restrict__ q, const float* __restrict__ kb,
        unsigned short* __restrict__ Q2, unsigned short* __restrict__ K2) {
    const int b = blockIdx.x;
    const bool isQ = (b < NROWS);
    const int r = isQ ? b : b - NROWS;
    const float* src = (isQ ? q : kb) + (size_t)r * DIM;
    unsigned short* D = (isQ ? Q2 : K2) + (size_t)r * DIM2;

    const int t = threadIdx.x;          // 0..127
    float4 v0 = *(const float4*)(src + t * 4);          // coalesced
    float4 v1 = *(const float4*)(src + 512 + t * 4);    // coalesced
    float s = v0.x * v0.x + v0.y * v0.y + v0.z * v0.z + v0.w * v0.w
            + v1.x * v1.x + v1.y * v1.y + v1.z * v1.z + v1.w * v1.w;
    for (int o = 32; o; o >>= 1) s += __shfl_down(s, o, 64);
    __shared__ float wsum[2];
    __shared__ float inv_s;
    int lane = t & 63, wid = t >> 6;
    if (lane == 0) wsum[wid] = s;
    __syncthreads();
    if (t == 0)
        inv_s = 1.0f / fmaxf(sqrtf(wsum[0] + wsum[1]), 1e-12f);
    __syncthreads();
    const float inv = inv_s;

    float xs[8] = {v0.x * inv, v0.y * inv, v0.z * inv, v0.w * inv,
                   v1.x * inv, v1.y * inv, v1.z * inv, v1.w * inv};
    bf16x8 hi, lo;
#pragma unroll
    for (int i = 0; i < 8; ++i) {
        unsigned short h = f2bf(xs[i]);
        hi[i] = (short)h;
        lo[i] = (short)f2bf(xs[i] - bf2f(h));
    }
    // chunk t: k-block t>>3, chunk-in-block t&7, swizzled by row&7
    const int off = (t >> 3) * 64 + (((t & 7) ^ (r & 7)) * 8);
    *(bf16x8*)(D + off)       = hi;
    *(bf16x8*)(D + DIM + off) = lo;
}

// --- 2) 256x128 transposed MFMA GEMM + in-register top-6 (r13 verbatim) -----
__global__ __launch_bounds__(256, 2) void gemm_topk_kernel(
        const unsigned short* __restrict__ Q2, const unsigned short* __restrict__ K2,
        float2* __restrict__ partials) {
    // K-loop: Ks[256*64] (32 KB) + Qs[128*64] (16 KB); merge: 128*PS float2
    __shared__ __align__(16) char smem[53248];
    unsigned short* Ks = (unsigned short*)smem;          // A-operand (keys)
    unsigned short* Qs = Ks + KBB * 64;                  // B-operand (queries)
    float2* mbuf = (float2*)smem;                        // [128 q][PS]

    const int tid = threadIdx.x;
    const int w = tid >> 6, l = tid & 63;
    const int l15 = l & 15, l4 = l >> 4;
    const int qbase = blockIdx.x * QB;
    const int kbase = blockIdx.y * KBB;
    const int wkh = w & 1;               // key half   (128 keys)
    const int wqh = w >> 1;              // query half (64 queries)

    const int arow  = tid >> 3;          // 0..31 (+ j*32)
    const int akoff = (tid & 7) * 8;     // swizzled position within k-block

    const int xr = l15 & 7;
    const int fa_row = (wkh * 128 + l15) * 64;   // + mt*1024
    const int fb_row = (wqh * 64 + l15) * 64;    // + nt*1024

    const size_t qstage = (size_t)(qbase + arow) * DIM2 + akoff;
    const size_t kstage = (size_t)(kbase + arow) * DIM2 + akoff;

    f32x4 acc[8][4];   // [mt = key-tile][nt = query-tile]
#pragma unroll
    for (int mt = 0; mt < 8; ++mt)
#pragma unroll
        for (int nt = 0; nt < 4; ++nt) acc[mt][nt] = (f32x4){0.f, 0.f, 0.f, 0.f};

#pragma unroll 1
    for (int k0 = 0; k0 < DIM2; k0 += 64) {
#pragma unroll
        for (int j = 0; j < 8; ++j)
            async16(K2 + kstage + (size_t)j * 32 * DIM2 + k0,
                    Ks + (tid + j * 256) * 8);
#pragma unroll
        for (int j = 0; j < 4; ++j)
            async16(Q2 + qstage + (size_t)j * 32 * DIM2 + k0,
                    Qs + (tid + j * 256) * 8);
        __syncthreads();   // drains vmcnt (global_load_lds)
#pragma unroll
        for (int ks = 0; ks < 2; ++ks) {
            const int p8 = ((ks * 4 + l4) ^ xr) * 8;
            bf16x8 af[8], bf[4];
#pragma unroll
            for (int mt = 0; mt < 8; ++mt)
                af[mt] = *(const bf16x8*)(Ks + fa_row + mt * 1024 + p8);
#pragma unroll
            for (int nt = 0; nt < 4; ++nt)
                bf[nt] = *(const bf16x8*)(Qs + fb_row + nt * 1024 + p8);
#pragma unroll
            for (int mt = 0; mt < 8; ++mt)
#pragma unroll
                for (int nt = 0; nt < 4; ++nt)
                    acc[mt][nt] = __builtin_amdgcn_mfma_f32_16x16x32_bf16(
                        af[mt], bf[nt], acc[mt][nt], 0, 0, 0);
        }
        __syncthreads();
    }

    // ---- in-register top-6 (once per block): 32 keys/thread per nt-list ----
    float tvl[4][6]; int til[4][6];
#pragma unroll
    for (int n = 0; n < 4; ++n)
#pragma unroll
        for (int i = 0; i < 6; ++i) { tvl[n][i] = -INFINITY; til[n][i] = 0x7fffffff; }

#pragma unroll
    for (int nt = 0; nt < 4; ++nt) {
#pragma unroll
        for (int mt = 0; mt < 8; ++mt) {
            const f32x4 a = acc[mt][nt];
            const float m4 = fmaxf(fmaxf(a.x, a.y), fmaxf(a.z, a.w));
            if (m4 > tvl[nt][5]) {
                const int kk = kbase + wkh * 128 + mt * 16 + l4 * 4;
                ins6(a.x, kk + 0, tvl[nt], til[nt]);
                ins6(a.y, kk + 1, tvl[nt], til[nt]);
                ins6(a.z, kk + 2, tvl[nt], til[nt]);
                ins6(a.w, kk + 3, tvl[nt], til[nt]);
            }
        }
    }

    // ---- block merge: 8 slots per query -> 1 list per query ---------------
    __syncthreads();                     // all K-loop LDS reads done
    const int slot = wkh * 4 + l4;       // 0..7
#pragma unroll
    for (int nt = 0; nt < 4; ++nt) {
        const int ql = wqh * 64 + nt * 16 + l15;     // local query 0..127
        float2* dst = mbuf + (size_t)ql * PS + slot * 6;
#pragma unroll
        for (int e = 0; e < 6; ++e)
            dst[e] = make_float2(tvl[nt][e], __int_as_float(til[nt][e]));
    }
    __syncthreads();

    if (tid < 128) {                     // one thread per query merges 8 lists
        float tv[6]; int ti[6];
#pragma unroll
        for (int i = 0; i < 6; ++i) { tv[i] = -INFINITY; ti[i] = 0x7fffffff; }
        const float2* src = mbuf + (size_t)tid * PS;
        for (int e = 0; e < 48; ++e) {
            float2 p = src[e];
            if (p.x < tv[5]) continue;
            insert6(p.x, __float_as_int(p.y), tv, ti);
        }
        size_t off = ((size_t)(qbase + tid) * NKB + blockIdx.y) * TOPK;
#pragma unroll
        for (int i = 0; i < 6; ++i)
            partials[off + i] = make_float2(tv[i], __int_as_float(ti[i]));
    }
}

// --- 3) parallel merge + fused finalize (device-scope handoff) --------------
__global__ __launch_bounds__(256) void merge_kernel(
        const float2* __restrict__ partials,
        const int* __restrict__ query_ids, const int* __restrict__ key_ids,
        int* __restrict__ counter, int* __restrict__ done,
        float* __restrict__ out) {
    __shared__ float2 lbuf[32][49];      // [row-in-block][8 parts * 6, pad 49]
    __shared__ int sc[32];
    const int tid  = threadIdx.x;
    const int rloc = tid >> 3;           // 0..31
    const int part = tid & 7;            // 0..7
    const int row  = blockIdx.x * 32 + rloc;

    // stage 1: each thread merges 4 of the 32 lists (24 entries, coalesced)
    float tv[6]; int ti[6];
#pragma unroll
    for (int i = 0; i < 6; ++i) { tv[i] = -INFINITY; ti[i] = 0x7fffffff; }
    const float2* src = partials + ((size_t)row * NKB + part * 4) * TOPK;
#pragma unroll
    for (int e = 0; e < 24; ++e) {
        float2 p = src[e];
        if (p.x < tv[5]) continue;
        insert6(p.x, __float_as_int(p.y), tv, ti);
    }
#pragma unroll
    for (int i = 0; i < 6; ++i)
        lbuf[rloc][part * 6 + i] = make_float2(tv[i], __int_as_float(ti[i]));
    __syncthreads();

    // stage 2: one thread per row merges the 8 partial lists + counts
    if (part == 0) {
        float tv2[6]; int ti2[6];
#pragma unroll
        for (int i = 0; i < 6; ++i) { tv2[i] = -INFINITY; ti2[i] = 0x7fffffff; }
#pragma unroll
        for (int e = 0; e < 48; ++e) {
            float2 p = lbuf[rloc][e];
            if (p.x < tv2[5]) continue;
            insert6(p.x, __float_as_int(p.y), tv2, ti2);
        }
        const int qid = query_ids[row];
        int cnt = 0;
#pragma unroll
        for (int r = 1; r < TOPK; ++r)
            cnt += (key_ids[ti2[r]] == qid) ? 1 : 0;
        sc[rloc] = cnt;
    }
    __syncthreads();
    if (tid == 0) {
        int c = 0;
#pragma unroll
        for (int i = 0; i < 32; ++i) c += sc[i];
        atomicAdd(counter, c);
        __threadfence();                 // counter-add visible before done-add
        int prev = atomicAdd(done, 1);
        if (prev == gridDim.x - 1) {     // last block finalizes
            int total = atomicAdd(counter, 0);   // coherent read
            out[0] = (float)total / (float)(NROWS * KSEL);
        }
    }
}

extern "C" void kernel_launch(void* const* d_in, const int* in_sizes, int n_in,
                              void* d_out, int out_size, void* d_ws, size_t ws_size,
                              hipStream_t stream) {
    (void)in_sizes; (void)n_in; (void)out_size; (void)ws_size;
    const int*   query_ids = (const int*)d_in[0];
    const int*   key_ids   = (const int*)d_in[1];
    const float* q         = (const float*)d_in[2];
    const float* kb        = (const float*)d_in[3];

    char* ws = (char*)d_ws;
    const size_t MB32 = (size_t)NROWS * DIM2 * sizeof(unsigned short);  // 32 MB
    int*            counter  = (int*)ws;          // [0]=matches, [1]=done
    unsigned short* Q2       = (unsigned short*)(ws + 256);
    unsigned short* K2       = (unsigned short*)(ws + 256 + MB32);
    float2*         partials = (float2*)(ws + 256 + 2 * MB32);

    hipMemsetAsync(counter, 0, 2 * sizeof(int), stream);
    prep_kernel<<<2 * NROWS, 128, 0, stream>>>(q, kb, Q2, K2);
    gemm_topk_kernel<<<dim3(NQB, NKB), 256, 0, stream>>>(Q2, K2, partials);
    merge_kernel<<<NROWS / 32, 256, 0, stream>>>(partials, query_ids, key_ids,
                                                 counter, counter + 1,
                                                 (float*)d_out);
}